// Round 1
// baseline (1142.407 us; speedup 1.0000x reference)
//
#include <hip/hip_runtime.h>
#include <hip/hip_bf16.h>
#include <cstdint>
#include <cstddef>

#define NN 100000
#define EE 1600000
#define GG 2048

constexpr int NB_SCAN = (NN + 255) / 256; // 391 blocks over nodes

__device__ __forceinline__ float lrelu(float v) { return v > 0.f ? v : 0.2f * v; }

// ---------------- CSR build (dst -> list of src), reused by all 3 layers ----
__global__ void k_count(const int* __restrict__ ei, int* __restrict__ deg) {
    int i = blockIdx.x * blockDim.x + threadIdx.x;
    if (i >= EE + NN) return;
    int d = (i < EE) ? ei[EE + i] : (i - EE);
    atomicAdd(&deg[d], 1);
}

__global__ void k_scan1(const int* __restrict__ deg, int* __restrict__ offs,
                        int* __restrict__ bsums) {
    __shared__ int tmp[256];
    int tid = threadIdx.x;
    int i = blockIdx.x * 256 + tid;
    int v = (i < NN) ? deg[i] : 0;
    tmp[tid] = v; __syncthreads();
    for (int off = 1; off < 256; off <<= 1) {
        int t = (tid >= off) ? tmp[tid - off] : 0;
        __syncthreads();
        tmp[tid] += t;
        __syncthreads();
    }
    if (i < NN) offs[i] = tmp[tid] - v;   // exclusive within block
    if (tid == 255) bsums[blockIdx.x] = tmp[255];
}

__global__ void k_scan2(int* __restrict__ bsums) {
    __shared__ int tmp[512];
    int tid = threadIdx.x;
    int v = (tid < NB_SCAN) ? bsums[tid] : 0;
    tmp[tid] = v; __syncthreads();
    for (int off = 1; off < 512; off <<= 1) {
        int t = (tid >= off) ? tmp[tid - off] : 0;
        __syncthreads();
        tmp[tid] += t;
        __syncthreads();
    }
    if (tid < NB_SCAN) bsums[tid] = tmp[tid] - v;  // exclusive block offsets
}

__global__ void k_scan3(int* __restrict__ offs, const int* __restrict__ bsums) {
    int i = blockIdx.x * 256 + threadIdx.x;
    if (i < NN) offs[i] += bsums[blockIdx.x];
}

__global__ void k_scatter(const int* __restrict__ ei, const int* __restrict__ offs,
                          int* __restrict__ cursor, int* __restrict__ col) {
    int i = blockIdx.x * blockDim.x + threadIdx.x;
    if (i >= EE + NN) return;
    int s, d;
    if (i < EE) { s = ei[i]; d = ei[EE + i]; } else { s = d = i - EE; }
    int pos = offs[d] + atomicAdd(&cursor[d], 1);
    col[pos] = s;
}

// ---------------- per-layer kernels ----------------------------------------
// H[row, j] = sum_k X[row, k] * W[k, j]; W is [fin, 64]
__global__ __launch_bounds__(256) void k_gemm(const float* __restrict__ X,
                                              const float* __restrict__ W,
                                              float* __restrict__ H, int fin) {
    __shared__ float xs[4 * 128];
    int j  = threadIdx.x;   // 0..63 output col
    int ty = threadIdx.y;   // 0..3 row within block
    int row0 = blockIdx.x * 4;
    int t = ty * 64 + j;
    int tot = 4 * fin;
    for (int idx = t; idx < tot; idx += 256) {
        int r = idx / fin, k = idx - r * fin;
        int rr = row0 + r;
        xs[idx] = (rr < NN) ? X[(size_t)rr * fin + k] : 0.f;
    }
    __syncthreads();
    int row = row0 + ty;
    if (row >= NN) return;
    const float* xr = xs + ty * fin;
    float acc = 0.f;
    for (int k = 0; k < fin; k++) acc += xr[k] * W[k * 64 + j];
    H[(size_t)row * 64 + j] = acc;
}

// attention logits: als[n,h] = <H[n,h,:], a_src[h,:]>, ald likewise
__global__ void k_al(const float* __restrict__ H, const float* __restrict__ asrc,
                     const float* __restrict__ adst, float* __restrict__ als,
                     float* __restrict__ ald) {
    int t = blockIdx.x * blockDim.x + threadIdx.x;
    if (t >= NN * 4) return;
    int n = t >> 2, h = t & 3;
    const float* hp = H + (size_t)n * 64 + h * 16;
    const float* sa = asrc + h * 16;
    const float* da = adst + h * 16;
    float s1 = 0.f, s2 = 0.f;
#pragma unroll
    for (int c = 0; c < 16; c++) { float v = hp[c]; s1 += v * sa[c]; s2 += v * da[c]; }
    als[t] = s1; ald[t] = s2;
}

// one wave per destination node: segment softmax + weighted gather, no atomics
__global__ __launch_bounds__(256) void k_agg(
    const float* __restrict__ H, const float* __restrict__ als,
    const float* __restrict__ ald, const int* __restrict__ offs,
    const int* __restrict__ deg, const int* __restrict__ col,
    const float* __restrict__ bias, float* __restrict__ Hout) {
    int lane = threadIdx.x & 63;
    int n = blockIdx.x * 4 + (threadIdx.x >> 6);
    if (n >= NN) return;
    int start = offs[n];
    int len = deg[n];
    float4 ad4 = ((const float4*)ald)[n];
    float adv[4] = {ad4.x, ad4.y, ad4.z, ad4.w};

    // phase 1: per-head max over incoming edges
    float mx[4] = {-1e30f, -1e30f, -1e30f, -1e30f};
    for (int e = lane; e < len; e += 64) {
        int s = col[start + e];
        float4 a = ((const float4*)als)[s];
        mx[0] = fmaxf(mx[0], lrelu(a.x + adv[0]));
        mx[1] = fmaxf(mx[1], lrelu(a.y + adv[1]));
        mx[2] = fmaxf(mx[2], lrelu(a.z + adv[2]));
        mx[3] = fmaxf(mx[3], lrelu(a.w + adv[3]));
    }
#pragma unroll
    for (int off = 32; off > 0; off >>= 1) {
#pragma unroll
        for (int h = 0; h < 4; h++) mx[h] = fmaxf(mx[h], __shfl_xor(mx[h], off, 64));
    }

    // phase 2: per-head sum of exp(e - max)
    float sm[4] = {0.f, 0.f, 0.f, 0.f};
    for (int e = lane; e < len; e += 64) {
        int s = col[start + e];
        float4 a = ((const float4*)als)[s];
        sm[0] += __expf(lrelu(a.x + adv[0]) - mx[0]);
        sm[1] += __expf(lrelu(a.y + adv[1]) - mx[1]);
        sm[2] += __expf(lrelu(a.z + adv[2]) - mx[2]);
        sm[3] += __expf(lrelu(a.w + adv[3]) - mx[3]);
    }
#pragma unroll
    for (int off = 32; off > 0; off >>= 1) {
#pragma unroll
        for (int h = 0; h < 4; h++) sm[h] += __shfl_xor(sm[h], off, 64);
    }

    // phase 3: weighted message gather; lane = output channel (head hh)
    int hh = lane >> 4;
    float mh = mx[hh];
    float ih = 1.f / (sm[hh] + 1e-16f);
    float ah = adv[hh];
    float acc = 0.f;
    for (int e = 0; e < len; e++) {
        int s = col[start + e];
        float alpha = __expf(lrelu(als[s * 4 + hh] + ah) - mh) * ih;
        acc += alpha * H[(size_t)s * 64 + lane];
    }
    float o = acc + bias[lane];
    Hout[(size_t)n * 64 + lane] = o > 0.f ? o : 0.f;  // fused bias + ReLU
}

// ---------------- pooling + head --------------------------------------------
__global__ void k_out_init(const float* __restrict__ head_b, float* __restrict__ out) {
    int g = blockIdx.x * blockDim.x + threadIdx.x;
    if (g < GG) out[g] = head_b[0];
}

__global__ void k_pool(const float* __restrict__ H, const int* __restrict__ batch,
                       const float* __restrict__ hw, float* __restrict__ out) {
    int n = blockIdx.x * blockDim.x + threadIdx.x;
    if (n >= NN) return;
    const float4* hp = (const float4*)(H + (size_t)n * 64);
    const float4* wp = (const float4*)hw;
    float t = 0.f;
#pragma unroll
    for (int k = 0; k < 16; k++) {
        float4 a = hp[k]; float4 b = wp[k];
        t += a.x * b.x + a.y * b.y + a.z * b.z + a.w * b.w;
    }
    atomicAdd(&out[batch[n]], t);
}

// ---------------- launch -----------------------------------------------------
extern "C" void kernel_launch(void* const* d_in, const int* in_sizes, int n_in,
                              void* d_out, int out_size, void* d_ws, size_t ws_size,
                              hipStream_t stream) {
    const float* x     = (const float*)d_in[0];
    const int*   ei    = (const int*)d_in[1];
    const int*   batch = (const int*)d_in[2];
    const float* Wm[3] = {(const float*)d_in[3], (const float*)d_in[7],  (const float*)d_in[11]};
    const float* As[3] = {(const float*)d_in[4], (const float*)d_in[8],  (const float*)d_in[12]};
    const float* Ad[3] = {(const float*)d_in[5], (const float*)d_in[9],  (const float*)d_in[13]};
    const float* Bb[3] = {(const float*)d_in[6], (const float*)d_in[10], (const float*)d_in[14]};
    const float* hw = (const float*)d_in[15];
    const float* hb = (const float*)d_in[16];
    float* out = (float*)d_out;

    uint8_t* w = (uint8_t*)d_ws;
    auto alloc = [&](size_t bytes) -> void* {
        void* p = (void*)w;
        w += (bytes + 255) & ~(size_t)255;
        return p;
    };
    float* A      = (float*)alloc((size_t)NN * 64 * 4);   // gemm output
    float* Bf     = (float*)alloc((size_t)NN * 64 * 4);   // aggregated output
    float* als    = (float*)alloc((size_t)NN * 4 * 4);
    float* ald    = (float*)alloc((size_t)NN * 4 * 4);
    int*   deg    = (int*)alloc((size_t)NN * 4);
    int*   offs   = (int*)alloc((size_t)NN * 4);
    int*   cursor = (int*)alloc((size_t)NN * 4);
    int*   col    = (int*)alloc((size_t)(EE + NN) * 4);
    int*   bsums  = (int*)alloc((size_t)((NB_SCAN + 63) & ~63) * 4);

    hipMemsetAsync(deg, 0, (size_t)NN * 4, stream);
    hipMemsetAsync(cursor, 0, (size_t)NN * 4, stream);

    int eb = (EE + NN + 255) / 256;
    k_count  <<<eb, 256, 0, stream>>>(ei, deg);
    k_scan1  <<<NB_SCAN, 256, 0, stream>>>(deg, offs, bsums);
    k_scan2  <<<1, 512, 0, stream>>>(bsums);
    k_scan3  <<<NB_SCAN, 256, 0, stream>>>(offs, bsums);
    k_scatter<<<eb, 256, 0, stream>>>(ei, offs, cursor, col);

    const float* cur_in = x;
    int fin = 128;
    for (int L = 0; L < 3; L++) {
        k_gemm<<<dim3((NN + 3) / 4), dim3(64, 4), 0, stream>>>(cur_in, Wm[L], A, fin);
        k_al  <<<(NN * 4 + 255) / 256, 256, 0, stream>>>(A, As[L], Ad[L], als, ald);
        k_agg <<<(NN + 3) / 4, 256, 0, stream>>>(A, als, ald, offs, deg, col, Bb[L], Bf);
        cur_in = Bf;
        fin = 64;
    }

    k_out_init<<<(GG + 255) / 256, 256, 0, stream>>>(hb, out);
    k_pool    <<<(NN + 255) / 256, 256, 0, stream>>>(Bf, batch, hw, out);
}

// Round 2
// 847.749 us; speedup vs baseline: 1.3476x; 1.3476x over previous
//
#include <hip/hip_runtime.h>
#include <hip/hip_bf16.h>
#include <cstdint>
#include <cstddef>

#define NN 100000
#define EE 1600000
#define GG 2048

constexpr int NB_SCAN = (NN + 255) / 256; // 391 blocks over nodes

__device__ __forceinline__ float lrelu(float v) { return v > 0.f ? v : 0.2f * v; }

// ---------------- CSR build (dst -> list of src), reused by all 3 layers ----
__global__ void k_count(const int* __restrict__ ei, int* __restrict__ deg) {
    int i = blockIdx.x * blockDim.x + threadIdx.x;
    if (i >= EE + NN) return;
    int d = (i < EE) ? ei[EE + i] : (i - EE);
    atomicAdd(&deg[d], 1);
}

__global__ void k_scan1(const int* __restrict__ deg, int* __restrict__ offs,
                        int* __restrict__ bsums) {
    __shared__ int tmp[256];
    int tid = threadIdx.x;
    int i = blockIdx.x * 256 + tid;
    int v = (i < NN) ? deg[i] : 0;
    tmp[tid] = v; __syncthreads();
    for (int off = 1; off < 256; off <<= 1) {
        int t = (tid >= off) ? tmp[tid - off] : 0;
        __syncthreads();
        tmp[tid] += t;
        __syncthreads();
    }
    if (i < NN) offs[i] = tmp[tid] - v;   // exclusive within block
    if (tid == 255) bsums[blockIdx.x] = tmp[255];
}

__global__ void k_scan2(int* __restrict__ bsums) {
    __shared__ int tmp[512];
    int tid = threadIdx.x;
    int v = (tid < NB_SCAN) ? bsums[tid] : 0;
    tmp[tid] = v; __syncthreads();
    for (int off = 1; off < 512; off <<= 1) {
        int t = (tid >= off) ? tmp[tid - off] : 0;
        __syncthreads();
        tmp[tid] += t;
        __syncthreads();
    }
    if (tid < NB_SCAN) bsums[tid] = tmp[tid] - v;  // exclusive block offsets
}

__global__ void k_scan3(int* __restrict__ offs, const int* __restrict__ bsums) {
    int i = blockIdx.x * 256 + threadIdx.x;
    if (i < NN) offs[i] += bsums[blockIdx.x];
}

__global__ void k_scatter(const int* __restrict__ ei, const int* __restrict__ offs,
                          int* __restrict__ cursor, int* __restrict__ col) {
    int i = blockIdx.x * blockDim.x + threadIdx.x;
    if (i >= EE + NN) return;
    int s, d;
    if (i < EE) { s = ei[i]; d = ei[EE + i]; } else { s = d = i - EE; }
    int pos = offs[d] + atomicAdd(&cursor[d], 1);
    col[pos] = s;
}

// ---------------- GEMM + fused attention-logit epilogue ---------------------
// H[row, j] = sum_k X[row, k] * W[k, j]; W is [fin, 64]
// epilogue: als[row,h] = sum_c H[row,h*16+c]*asrc[h*16+c]; ald likewise
__global__ __launch_bounds__(256) void k_gemm(const float* __restrict__ X,
                                              const float* __restrict__ W,
                                              const float* __restrict__ asrc,
                                              const float* __restrict__ adst,
                                              float* __restrict__ H,
                                              float* __restrict__ als,
                                              float* __restrict__ ald, int fin) {
    __shared__ float xs[4 * 128];
    int j  = threadIdx.x;   // 0..63 output col; one wave == one row
    int ty = threadIdx.y;   // 0..3 row within block
    int row0 = blockIdx.x * 4;
    int t = ty * 64 + j;
    int tot = 4 * fin;
    for (int idx = t; idx < tot; idx += 256) {
        int r = idx / fin, k = idx - r * fin;
        int rr = row0 + r;
        xs[idx] = (rr < NN) ? X[(size_t)rr * fin + k] : 0.f;
    }
    __syncthreads();
    int row = row0 + ty;
    if (row >= NN) return;
    const float* xr = xs + ty * fin;
    float acc = 0.f;
    for (int k = 0; k < fin; k++) acc += xr[k] * W[k * 64 + j];
    H[(size_t)row * 64 + j] = acc;
    // fused attention logits: reduce acc*a within each 16-lane head group
    float vs = acc * asrc[j];
    float vd = acc * adst[j];
#pragma unroll
    for (int off = 8; off > 0; off >>= 1) {
        vs += __shfl_xor(vs, off, 64);
        vd += __shfl_xor(vd, off, 64);
    }
    if ((j & 15) == 0) {
        int h = j >> 4;
        als[(size_t)row * 4 + h] = vs;
        ald[(size_t)row * 4 + h] = vd;
    }
}

// one wave per destination node: single-pass segment softmax + weighted gather
__global__ __launch_bounds__(256) void k_agg(
    const float* __restrict__ H, const float* __restrict__ als,
    const float* __restrict__ ald, const int* __restrict__ offs,
    const int* __restrict__ deg, const int* __restrict__ col,
    const float* __restrict__ bias, float* __restrict__ Hout,
    const int* __restrict__ batch, const float* __restrict__ hw,
    float* __restrict__ out, int last) {
    __shared__ float lws[4][64 * 4];  // per-wave: unnormalized weights [e][h]
    __shared__ int   lsi[4][64];      // per-wave: src index per edge
    int lane = threadIdx.x & 63;
    int wid  = threadIdx.x >> 6;
    int n = blockIdx.x * 4 + wid;
    if (n >= NN) return;
    int start = offs[n];
    int len = deg[n];
    float4 ad4 = ((const float4*)ald)[n];
    float adv[4] = {ad4.x, ad4.y, ad4.z, ad4.w};
    int hh = lane >> 4;
    float acc0 = 0.f, acc1 = 0.f, acc2 = 0.f, acc3 = 0.f;
    float inv = 1.f;

    if (len <= 64) {
        // lane e owns edge e: one load of col + als, one exp
        float ev0 = -1e30f, ev1 = -1e30f, ev2 = -1e30f, ev3 = -1e30f;
        int s = 0;
        if (lane < len) {
            s = col[start + lane];
            float4 a = ((const float4*)als)[s];
            ev0 = lrelu(a.x + adv[0]); ev1 = lrelu(a.y + adv[1]);
            ev2 = lrelu(a.z + adv[2]); ev3 = lrelu(a.w + adv[3]);
        }
        float m0 = ev0, m1 = ev1, m2 = ev2, m3 = ev3;
#pragma unroll
        for (int off = 32; off > 0; off >>= 1) {
            m0 = fmaxf(m0, __shfl_xor(m0, off, 64));
            m1 = fmaxf(m1, __shfl_xor(m1, off, 64));
            m2 = fmaxf(m2, __shfl_xor(m2, off, 64));
            m3 = fmaxf(m3, __shfl_xor(m3, off, 64));
        }
        float w0 = 0.f, w1 = 0.f, w2 = 0.f, w3 = 0.f;
        if (lane < len) {
            w0 = __expf(ev0 - m0); w1 = __expf(ev1 - m1);
            w2 = __expf(ev2 - m2); w3 = __expf(ev3 - m3);
        }
        float s0 = w0, s1 = w1, s2 = w2, s3 = w3;
#pragma unroll
        for (int off = 32; off > 0; off >>= 1) {
            s0 += __shfl_xor(s0, off, 64); s1 += __shfl_xor(s1, off, 64);
            s2 += __shfl_xor(s2, off, 64); s3 += __shfl_xor(s3, off, 64);
        }
        if (lane < len) {
            ((float4*)&lws[wid][lane * 4])[0] = make_float4(w0, w1, w2, w3);
            lsi[wid][lane] = s;
        }
        // wave-synchronous: same wave wrote these LDS slots; DS ops in-order
        float smh = hh == 0 ? s0 : hh == 1 ? s1 : hh == 2 ? s2 : s3;
        inv = 1.f / (smh + 1e-16f);
        int e = 0;
        for (; e + 4 <= len; e += 4) {   // 4 independent gathers in flight
            int sa = lsi[wid][e],     sb = lsi[wid][e + 1];
            int sc = lsi[wid][e + 2], sd = lsi[wid][e + 3];
            float wa = lws[wid][e * 4 + hh],       wb = lws[wid][(e + 1) * 4 + hh];
            float wc = lws[wid][(e + 2) * 4 + hh], wd = lws[wid][(e + 3) * 4 + hh];
            float ha = H[(size_t)sa * 64 + lane];
            float hb = H[(size_t)sb * 64 + lane];
            float hc = H[(size_t)sc * 64 + lane];
            float hd = H[(size_t)sd * 64 + lane];
            acc0 += wa * ha; acc1 += wb * hb; acc2 += wc * hc; acc3 += wd * hd;
        }
        for (; e < len; e++) {
            int sa = lsi[wid][e];
            acc0 += lws[wid][e * 4 + hh] * H[(size_t)sa * 64 + lane];
        }
    } else {
        // rare fallback: old 3-phase path, normalized inline (inv stays 1)
        float mx[4] = {-1e30f, -1e30f, -1e30f, -1e30f};
        for (int e = lane; e < len; e += 64) {
            int s = col[start + e];
            float4 a = ((const float4*)als)[s];
            mx[0] = fmaxf(mx[0], lrelu(a.x + adv[0]));
            mx[1] = fmaxf(mx[1], lrelu(a.y + adv[1]));
            mx[2] = fmaxf(mx[2], lrelu(a.z + adv[2]));
            mx[3] = fmaxf(mx[3], lrelu(a.w + adv[3]));
        }
#pragma unroll
        for (int off = 32; off > 0; off >>= 1)
#pragma unroll
            for (int h = 0; h < 4; h++) mx[h] = fmaxf(mx[h], __shfl_xor(mx[h], off, 64));
        float sm[4] = {0.f, 0.f, 0.f, 0.f};
        for (int e = lane; e < len; e += 64) {
            int s = col[start + e];
            float4 a = ((const float4*)als)[s];
            sm[0] += __expf(lrelu(a.x + adv[0]) - mx[0]);
            sm[1] += __expf(lrelu(a.y + adv[1]) - mx[1]);
            sm[2] += __expf(lrelu(a.z + adv[2]) - mx[2]);
            sm[3] += __expf(lrelu(a.w + adv[3]) - mx[3]);
        }
#pragma unroll
        for (int off = 32; off > 0; off >>= 1)
#pragma unroll
            for (int h = 0; h < 4; h++) sm[h] += __shfl_xor(sm[h], off, 64);
        float mh = mx[hh];
        float ih = 1.f / (sm[hh] + 1e-16f);
        float ah = adv[hh];
        for (int e = 0; e < len; e++) {
            int s = col[start + e];
            float alpha = __expf(lrelu(als[(size_t)s * 4 + hh] + ah) - mh) * ih;
            acc0 += alpha * H[(size_t)s * 64 + lane];
        }
    }

    float o = (acc0 + acc1 + acc2 + acc3) * inv + bias[lane];
    o = fmaxf(o, 0.f);                   // fused bias + ReLU
    if (!last) {
        Hout[(size_t)n * 64 + lane] = o;
    } else {
        // fused sum-pool + head linear: one atomic per node
        float t = o * hw[lane];
#pragma unroll
        for (int off = 32; off > 0; off >>= 1) t += __shfl_xor(t, off, 64);
        if (lane == 0) atomicAdd(&out[batch[n]], t);
    }
}

// ---------------- output init ------------------------------------------------
__global__ void k_out_init(const float* __restrict__ head_b, float* __restrict__ out) {
    int g = blockIdx.x * blockDim.x + threadIdx.x;
    if (g < GG) out[g] = head_b[0];
}

// ---------------- launch -----------------------------------------------------
extern "C" void kernel_launch(void* const* d_in, const int* in_sizes, int n_in,
                              void* d_out, int out_size, void* d_ws, size_t ws_size,
                              hipStream_t stream) {
    const float* x     = (const float*)d_in[0];
    const int*   ei    = (const int*)d_in[1];
    const int*   batch = (const int*)d_in[2];
    const float* Wm[3] = {(const float*)d_in[3], (const float*)d_in[7],  (const float*)d_in[11]};
    const float* As[3] = {(const float*)d_in[4], (const float*)d_in[8],  (const float*)d_in[12]};
    const float* Ad[3] = {(const float*)d_in[5], (const float*)d_in[9],  (const float*)d_in[13]};
    const float* Bb[3] = {(const float*)d_in[6], (const float*)d_in[10], (const float*)d_in[14]};
    const float* hw = (const float*)d_in[15];
    const float* hb = (const float*)d_in[16];
    float* out = (float*)d_out;

    uint8_t* w = (uint8_t*)d_ws;
    auto alloc = [&](size_t bytes) -> void* {
        void* p = (void*)w;
        w += (bytes + 255) & ~(size_t)255;
        return p;
    };
    float* A      = (float*)alloc((size_t)NN * 64 * 4);   // gemm output
    float* Bf     = (float*)alloc((size_t)NN * 64 * 4);   // aggregated output
    float* als    = (float*)alloc((size_t)NN * 4 * 4);
    float* ald    = (float*)alloc((size_t)NN * 4 * 4);
    int*   deg    = (int*)alloc((size_t)NN * 4);
    int*   offs   = (int*)alloc((size_t)NN * 4);
    int*   cursor = (int*)alloc((size_t)NN * 4);
    int*   col    = (int*)alloc((size_t)(EE + NN) * 4);
    int*   bsums  = (int*)alloc((size_t)((NB_SCAN + 63) & ~63) * 4);

    hipMemsetAsync(deg, 0, (size_t)NN * 4, stream);
    hipMemsetAsync(cursor, 0, (size_t)NN * 4, stream);

    int eb = (EE + NN + 255) / 256;
    k_count  <<<eb, 256, 0, stream>>>(ei, deg);
    k_scan1  <<<NB_SCAN, 256, 0, stream>>>(deg, offs, bsums);
    k_scan2  <<<1, 512, 0, stream>>>(bsums);
    k_scan3  <<<NB_SCAN, 256, 0, stream>>>(offs, bsums);
    k_scatter<<<eb, 256, 0, stream>>>(ei, offs, cursor, col);
    k_out_init<<<(GG + 255) / 256, 256, 0, stream>>>(hb, out);

    const float* cur_in = x;
    int fin = 128;
    for (int L = 0; L < 3; L++) {
        k_gemm<<<dim3((NN + 3) / 4), dim3(64, 4), 0, stream>>>(
            cur_in, Wm[L], As[L], Ad[L], A, als, ald, fin);
        k_agg <<<(NN + 3) / 4, 256, 0, stream>>>(
            A, als, ald, offs, deg, col, Bb[L], Bf, batch, hw, out, (L == 2) ? 1 : 0);
        cur_in = Bf;
        fin = 64;
    }
}

// Round 3
// 817.225 us; speedup vs baseline: 1.3979x; 1.0374x over previous
//
#include <hip/hip_runtime.h>
#include <hip/hip_bf16.h>
#include <cstdint>
#include <cstddef>

#define NN 100000
#define EE 1600000
#define GG 2048

constexpr int NB_SCAN = (NN + 255) / 256; // 391 blocks over nodes

__device__ __forceinline__ float lrelu(float v) { return v > 0.f ? v : 0.2f * v; }

// ---------------- CSR build (dst -> list of src), reused by all 3 layers ----
__global__ void k_count(const int* __restrict__ ei, int* __restrict__ deg) {
    int i = blockIdx.x * blockDim.x + threadIdx.x;
    if (i >= EE + NN) return;
    int d = (i < EE) ? ei[EE + i] : (i - EE);
    atomicAdd(&deg[d], 1);
}

__global__ void k_scan1(const int* __restrict__ deg, int* __restrict__ offs,
                        int* __restrict__ bsums) {
    __shared__ int tmp[256];
    int tid = threadIdx.x;
    int i = blockIdx.x * 256 + tid;
    int v = (i < NN) ? deg[i] : 0;
    tmp[tid] = v; __syncthreads();
    for (int off = 1; off < 256; off <<= 1) {
        int t = (tid >= off) ? tmp[tid - off] : 0;
        __syncthreads();
        tmp[tid] += t;
        __syncthreads();
    }
    if (i < NN) offs[i] = tmp[tid] - v;   // exclusive within block
    if (tid == 255) bsums[blockIdx.x] = tmp[255];
}

__global__ void k_scan2(int* __restrict__ bsums) {
    __shared__ int tmp[512];
    int tid = threadIdx.x;
    int v = (tid < NB_SCAN) ? bsums[tid] : 0;
    tmp[tid] = v; __syncthreads();
    for (int off = 1; off < 512; off <<= 1) {
        int t = (tid >= off) ? tmp[tid - off] : 0;
        __syncthreads();
        tmp[tid] += t;
        __syncthreads();
    }
    if (tid < NB_SCAN) bsums[tid] = tmp[tid] - v;  // exclusive block offsets
}

__global__ void k_scan3(int* __restrict__ offs, const int* __restrict__ bsums) {
    int i = blockIdx.x * 256 + threadIdx.x;
    if (i < NN) offs[i] += bsums[blockIdx.x];
}

__global__ void k_scatter(const int* __restrict__ ei, const int* __restrict__ offs,
                          int* __restrict__ cursor, int* __restrict__ col) {
    int i = blockIdx.x * blockDim.x + threadIdx.x;
    if (i >= EE + NN) return;
    int s, d;
    if (i < EE) { s = ei[i]; d = ei[EE + i]; } else { s = d = i - EE; }
    int pos = offs[d] + atomicAdd(&cursor[d], 1);
    col[pos] = s;
}

// ---------------- GEMM + fused attention-logit epilogue ---------------------
// 16 rows per block, 4 rows per thread; one W load feeds 4 FMAs.
// NN % 16 == 0, so no row bounds checks.
__global__ __launch_bounds__(256) void k_gemm(const float* __restrict__ X,
                                              const float* __restrict__ W,
                                              const float* __restrict__ asrc,
                                              const float* __restrict__ adst,
                                              float* __restrict__ H,
                                              float* __restrict__ als,
                                              float* __restrict__ ald, int fin) {
    __shared__ float xs[16 * 128];
    int j  = threadIdx.x & 63;   // output col; one wave handles 4 rows
    int ty = threadIdx.x >> 6;   // wave id 0..3
    int row0 = blockIdx.x * 16;
    int f4 = fin >> 2;                         // float4 per row (32 or 16)
    int lg = (fin == 128) ? 5 : 4;             // log2(f4)
    const float4* X4 = (const float4*)X;
    int tot4 = 16 * f4;
    for (int idx = threadIdx.x; idx < tot4; idx += 256) {
        int r = idx >> lg, k4 = idx & (f4 - 1);
        ((float4*)xs)[idx] = X4[(size_t)(row0 + r) * f4 + k4];
    }
    __syncthreads();
    const float* x0 = xs + (ty * 4 + 0) * fin;
    const float* x1 = xs + (ty * 4 + 1) * fin;
    const float* x2 = xs + (ty * 4 + 2) * fin;
    const float* x3 = xs + (ty * 4 + 3) * fin;
    float a0 = 0.f, a1 = 0.f, a2 = 0.f, a3 = 0.f;
    for (int k = 0; k < fin; k++) {
        float w = W[k * 64 + j];
        a0 += x0[k] * w; a1 += x1[k] * w; a2 += x2[k] * w; a3 += x3[k] * w;
    }
    int row = row0 + ty * 4;
    H[(size_t)(row + 0) * 64 + j] = a0;
    H[(size_t)(row + 1) * 64 + j] = a1;
    H[(size_t)(row + 2) * 64 + j] = a2;
    H[(size_t)(row + 3) * 64 + j] = a3;
    // fused attention logits: reduce acc*a within each 16-lane head group
    float asj = asrc[j], adj = adst[j];
    float accs[4] = {a0, a1, a2, a3};
#pragma unroll
    for (int r = 0; r < 4; r++) {
        float vs = accs[r] * asj;
        float vd = accs[r] * adj;
#pragma unroll
        for (int off = 8; off > 0; off >>= 1) {
            vs += __shfl_xor(vs, off, 64);
            vd += __shfl_xor(vd, off, 64);
        }
        if ((j & 15) == 0) {
            int h = j >> 4;
            als[(size_t)(row + r) * 4 + h] = vs;
            ald[(size_t)(row + r) * 4 + h] = vd;
        }
    }
}

// one wave per destination node: single-pass segment softmax + pair-gather
__global__ __launch_bounds__(256) void k_agg(
    const float* __restrict__ H, const float* __restrict__ als,
    const float* __restrict__ ald, const int* __restrict__ offs,
    const int* __restrict__ deg, const int* __restrict__ col,
    const float* __restrict__ bias, float* __restrict__ Hout,
    const int* __restrict__ batch, const float* __restrict__ hw,
    float* __restrict__ out, int last) {
    __shared__ float lws[4][64 * 4];  // per-wave: unnormalized weights [e][h]
    __shared__ int   lsi[4][64];      // per-wave: src index per edge
    int lane = threadIdx.x & 63;
    int wid  = threadIdx.x >> 6;
    int n = blockIdx.x * 4 + wid;
    if (n >= NN) return;
    int start = offs[n];
    int len = deg[n];
    float4 ad4 = ((const float4*)ald)[n];
    float adv[4] = {ad4.x, ad4.y, ad4.z, ad4.w};

    if (len <= 64) {
        // ---- softmax: lane e owns edge e ----
        float ev0 = -1e30f, ev1 = -1e30f, ev2 = -1e30f, ev3 = -1e30f;
        int s = 0;
        if (lane < len) {
            s = col[start + lane];
            float4 a = ((const float4*)als)[s];
            ev0 = lrelu(a.x + adv[0]); ev1 = lrelu(a.y + adv[1]);
            ev2 = lrelu(a.z + adv[2]); ev3 = lrelu(a.w + adv[3]);
        }
        float m0 = ev0, m1 = ev1, m2 = ev2, m3 = ev3;
#pragma unroll
        for (int off = 32; off > 0; off >>= 1) {
            m0 = fmaxf(m0, __shfl_xor(m0, off, 64));
            m1 = fmaxf(m1, __shfl_xor(m1, off, 64));
            m2 = fmaxf(m2, __shfl_xor(m2, off, 64));
            m3 = fmaxf(m3, __shfl_xor(m3, off, 64));
        }
        float w0 = 0.f, w1 = 0.f, w2 = 0.f, w3 = 0.f;
        if (lane < len) {
            w0 = __expf(ev0 - m0); w1 = __expf(ev1 - m1);
            w2 = __expf(ev2 - m2); w3 = __expf(ev3 - m3);
        }
        float s0 = w0, s1 = w1, s2 = w2, s3 = w3;
#pragma unroll
        for (int off = 32; off > 0; off >>= 1) {
            s0 += __shfl_xor(s0, off, 64); s1 += __shfl_xor(s1, off, 64);
            s2 += __shfl_xor(s2, off, 64); s3 += __shfl_xor(s3, off, 64);
        }
        if (lane < len) {
            ((float4*)&lws[wid][lane * 4])[0] = make_float4(w0, w1, w2, w3);
            lsi[wid][lane] = s;
        }
        // ---- pair-gather: lane handles float2 channel-pair c2 of edge e+sub ----
        int sub = lane >> 5;       // which row of the in-flight pair
        int c2  = lane & 31;       // channel pair index (channels 2c2, 2c2+1)
        int hh2 = c2 >> 3;         // head of this channel pair
        float smh = hh2 == 0 ? s0 : hh2 == 1 ? s1 : hh2 == 2 ? s2 : s3;
        float inv = 1.f / (smh + 1e-16f);
        const float2* H2 = (const float2*)H;
        float2 acc0 = {0.f, 0.f}, acc1 = {0.f, 0.f}, acc2 = {0.f, 0.f}, acc3 = {0.f, 0.f};
        int e = 0;
        for (; e + 8 <= len; e += 8) {   // 8 rows (4 pair-loads) in flight
            int sa = lsi[wid][e + 0 + sub], sb = lsi[wid][e + 2 + sub];
            int sc = lsi[wid][e + 4 + sub], sd = lsi[wid][e + 6 + sub];
            float wa = lws[wid][(e + 0 + sub) * 4 + hh2];
            float wb = lws[wid][(e + 2 + sub) * 4 + hh2];
            float wc = lws[wid][(e + 4 + sub) * 4 + hh2];
            float wd = lws[wid][(e + 6 + sub) * 4 + hh2];
            float2 ha = H2[(size_t)sa * 32 + c2];
            float2 hb = H2[(size_t)sb * 32 + c2];
            float2 hc = H2[(size_t)sc * 32 + c2];
            float2 hd = H2[(size_t)sd * 32 + c2];
            acc0.x += wa * ha.x; acc0.y += wa * ha.y;
            acc1.x += wb * hb.x; acc1.y += wb * hb.y;
            acc2.x += wc * hc.x; acc2.y += wc * hc.y;
            acc3.x += wd * hd.x; acc3.y += wd * hd.y;
        }
        for (; e < len; e += 2) {        // pair tail (odd edge: sub=1 gets w=0)
            int idx = e + sub;
            int valid = idx < len;
            int sa = lsi[wid][valid ? idx : 0];
            float wa = valid ? lws[wid][idx * 4 + hh2] : 0.f;
            float2 ha = H2[(size_t)sa * 32 + c2];
            acc0.x += wa * ha.x; acc0.y += wa * ha.y;
        }
        float2 acc;
        acc.x = acc0.x + acc1.x + acc2.x + acc3.x;
        acc.y = acc0.y + acc1.y + acc2.y + acc3.y;
        acc.x += __shfl_xor(acc.x, 32, 64);   // combine even/odd edge halves
        acc.y += __shfl_xor(acc.y, 32, 64);
        float2 b2 = ((const float2*)bias)[c2];
        float ox = fmaxf(acc.x * inv + b2.x, 0.f);
        float oy = fmaxf(acc.y * inv + b2.y, 0.f);
        if (!last) {
            if (sub == 0) ((float2*)(Hout + (size_t)n * 64))[c2] = make_float2(ox, oy);
        } else {
            float2 hw2 = ((const float2*)hw)[c2];
            float t = (sub == 0) ? (ox * hw2.x + oy * hw2.y) : 0.f;
#pragma unroll
            for (int off = 32; off > 0; off >>= 1) t += __shfl_xor(t, off, 64);
            if (lane == 0) atomicAdd(&out[batch[n]], t);
        }
        return;
    }

    // rare fallback (len > 64): 3-phase path, lane = channel
    int hh = lane >> 4;
    float mx[4] = {-1e30f, -1e30f, -1e30f, -1e30f};
    for (int e = lane; e < len; e += 64) {
        int s = col[start + e];
        float4 a = ((const float4*)als)[s];
        mx[0] = fmaxf(mx[0], lrelu(a.x + adv[0]));
        mx[1] = fmaxf(mx[1], lrelu(a.y + adv[1]));
        mx[2] = fmaxf(mx[2], lrelu(a.z + adv[2]));
        mx[3] = fmaxf(mx[3], lrelu(a.w + adv[3]));
    }
#pragma unroll
    for (int off = 32; off > 0; off >>= 1)
#pragma unroll
        for (int h = 0; h < 4; h++) mx[h] = fmaxf(mx[h], __shfl_xor(mx[h], off, 64));
    float sm[4] = {0.f, 0.f, 0.f, 0.f};
    for (int e = lane; e < len; e += 64) {
        int s = col[start + e];
        float4 a = ((const float4*)als)[s];
        sm[0] += __expf(lrelu(a.x + adv[0]) - mx[0]);
        sm[1] += __expf(lrelu(a.y + adv[1]) - mx[1]);
        sm[2] += __expf(lrelu(a.z + adv[2]) - mx[2]);
        sm[3] += __expf(lrelu(a.w + adv[3]) - mx[3]);
    }
#pragma unroll
    for (int off = 32; off > 0; off >>= 1)
#pragma unroll
        for (int h = 0; h < 4; h++) sm[h] += __shfl_xor(sm[h], off, 64);
    float mh = mx[hh];
    float ih = 1.f / (sm[hh] + 1e-16f);
    float ah = adv[hh];
    float acc = 0.f;
    for (int e = 0; e < len; e++) {
        int s = col[start + e];
        float alpha = __expf(lrelu(als[(size_t)s * 4 + hh] + ah) - mh) * ih;
        acc += alpha * H[(size_t)s * 64 + lane];
    }
    float o = fmaxf(acc + bias[lane], 0.f);
    if (!last) {
        Hout[(size_t)n * 64 + lane] = o;
    } else {
        float t = o * hw[lane];
#pragma unroll
        for (int off = 32; off > 0; off >>= 1) t += __shfl_xor(t, off, 64);
        if (lane == 0) atomicAdd(&out[batch[n]], t);
    }
}

// ---------------- output init ------------------------------------------------
__global__ void k_out_init(const float* __restrict__ head_b, float* __restrict__ out) {
    int g = blockIdx.x * blockDim.x + threadIdx.x;
    if (g < GG) out[g] = head_b[0];
}

// ---------------- launch -----------------------------------------------------
extern "C" void kernel_launch(void* const* d_in, const int* in_sizes, int n_in,
                              void* d_out, int out_size, void* d_ws, size_t ws_size,
                              hipStream_t stream) {
    const float* x     = (const float*)d_in[0];
    const int*   ei    = (const int*)d_in[1];
    const int*   batch = (const int*)d_in[2];
    const float* Wm[3] = {(const float*)d_in[3], (const float*)d_in[7],  (const float*)d_in[11]};
    const float* As[3] = {(const float*)d_in[4], (const float*)d_in[8],  (const float*)d_in[12]};
    const float* Ad[3] = {(const float*)d_in[5], (const float*)d_in[9],  (const float*)d_in[13]};
    const float* Bb[3] = {(const float*)d_in[6], (const float*)d_in[10], (const float*)d_in[14]};
    const float* hw = (const float*)d_in[15];
    const float* hb = (const float*)d_in[16];
    float* out = (float*)d_out;

    uint8_t* w = (uint8_t*)d_ws;
    auto alloc = [&](size_t bytes) -> void* {
        void* p = (void*)w;
        w += (bytes + 255) & ~(size_t)255;
        return p;
    };
    float* A      = (float*)alloc((size_t)NN * 64 * 4);   // gemm output
    float* Bf     = (float*)alloc((size_t)NN * 64 * 4);   // aggregated output
    float* als    = (float*)alloc((size_t)NN * 4 * 4);
    float* ald    = (float*)alloc((size_t)NN * 4 * 4);
    int*   deg    = (int*)alloc((size_t)NN * 4);
    int*   offs   = (int*)alloc((size_t)NN * 4);
    int*   cursor = (int*)alloc((size_t)NN * 4);
    int*   col    = (int*)alloc((size_t)(EE + NN) * 4);
    int*   bsums  = (int*)alloc((size_t)((NB_SCAN + 63) & ~63) * 4);

    hipMemsetAsync(deg, 0, (size_t)NN * 4, stream);
    hipMemsetAsync(cursor, 0, (size_t)NN * 4, stream);

    int eb = (EE + NN + 255) / 256;
    k_count  <<<eb, 256, 0, stream>>>(ei, deg);
    k_scan1  <<<NB_SCAN, 256, 0, stream>>>(deg, offs, bsums);
    k_scan2  <<<1, 512, 0, stream>>>(bsums);
    k_scan3  <<<NB_SCAN, 256, 0, stream>>>(offs, bsums);
    k_scatter<<<eb, 256, 0, stream>>>(ei, offs, cursor, col);
    k_out_init<<<(GG + 255) / 256, 256, 0, stream>>>(hb, out);

    const float* cur_in = x;
    int fin = 128;
    for (int L = 0; L < 3; L++) {
        k_gemm<<<NN / 16, 256, 0, stream>>>(
            cur_in, Wm[L], As[L], Ad[L], A, als, ald, fin);
        k_agg <<<(NN + 3) / 4, 256, 0, stream>>>(
            A, als, ald, offs, deg, col, Bb[L], Bf, batch, hw, out, (L == 2) ? 1 : 0);
        cur_in = Bf;
        fin = 64;
    }
}